// Round 1
// 719.826 us; speedup vs baseline: 1.1294x; 1.1294x over previous
//
#include <hip/hip_runtime.h>

#define B_ 4
#define C_ 512
#define L_ 4096

typedef __attribute__((ext_vector_type(8))) short bf16x8;
typedef __attribute__((ext_vector_type(4))) float f32x4;

static __device__ __forceinline__ unsigned short f2bf_rne(float f) {
  unsigned u = __float_as_uint(f);
  u += 0x7FFFu + ((u >> 16) & 1u);  // round-to-nearest-even
  return (unsigned short)(u >> 16);
}
static __device__ __forceinline__ unsigned pack_rne(float a, float b) {
  return (unsigned)f2bf_rne(a) | ((unsigned)f2bf_rne(b) << 16);
}
static __device__ __forceinline__ unsigned pack_trunc(float a, float b) {
  return (__float_as_uint(a) >> 16) | (__float_as_uint(b) & 0xFFFF0000u);
}
static __device__ __forceinline__ float bflo2f(unsigned w) {
  return __uint_as_float(w << 16);
}
static __device__ __forceinline__ float bfhi2f(unsigned w) {
  return __uint_as_float(w & 0xFFFF0000u);
}

// async global -> LDS, 16 B/lane; LDS dest = wave-uniform base + lane*16.
static __device__ __forceinline__ void g2lds16(const unsigned short* g,
                                               unsigned short* l) {
  __builtin_amdgcn_global_load_lds(
      (const __attribute__((address_space(1))) unsigned int*)g,
      (__attribute__((address_space(3))) unsigned int*)l, 16, 0, 0);
}

// ---------------------------------------------------------------------------
// K0: Q,K fp32 (C,L) -> Qt,Kt bf16 (L,C).  grid (L/64, C/64, B*2), block 256
// ---------------------------------------------------------------------------
__global__ __launch_bounds__(256) void transpose_cast_k(
    const float* __restrict__ Q, const float* __restrict__ K,
    unsigned short* __restrict__ Qt, unsigned short* __restrict__ Kt) {
  int zb = blockIdx.z;
  int b = zb >> 1;
  const float* src = ((zb & 1) ? K : Q) + (size_t)b * C_ * L_;
  unsigned short* dst = ((zb & 1) ? Kt : Qt) + (size_t)b * L_ * C_;
  int i0 = blockIdx.x * 64, c0 = blockIdx.y * 64;
  __shared__ float tile[64][65];
  int t = threadIdx.x;
  int cr = t >> 2, ig = (t & 3) * 16;
  const float* s = src + (size_t)(c0 + cr) * L_ + i0 + ig;
#pragma unroll
  for (int q = 0; q < 4; ++q) {
    float4 v = *(const float4*)(s + 4 * q);
    tile[cr][ig + 4 * q + 0] = v.x;
    tile[cr][ig + 4 * q + 1] = v.y;
    tile[cr][ig + 4 * q + 2] = v.z;
    tile[cr][ig + 4 * q + 3] = v.w;
  }
  __syncthreads();
  int ir = t >> 2, cg = (t & 3) * 16;
  unsigned wds[8];
#pragma unroll
  for (int k = 0; k < 8; ++k)
    wds[k] = pack_rne(tile[cg + 2 * k][ir], tile[cg + 2 * k + 1][ir]);
  unsigned short* d = dst + (size_t)(i0 + ir) * C_ + c0 + cg;
  uint4 o0, o1;
  o0.x = wds[0]; o0.y = wds[1]; o0.z = wds[2]; o0.w = wds[3];
  o1.x = wds[4]; o1.y = wds[5]; o1.z = wds[6]; o1.w = wds[7];
  *(uint4*)d = o0;
  *(uint4*)(d + 8) = o1;
}

// ---------------------------------------------------------------------------
// K0b: Vb[b,c,j] = bf16(V[b,c,j] * mask[b,j])   (mask binary: mask^2 == mask)
// ---------------------------------------------------------------------------
__global__ __launch_bounds__(256) void cast_v_k(
    const float* __restrict__ V, const float* __restrict__ mask,
    unsigned short* __restrict__ Vb) {
  size_t idx = ((size_t)blockIdx.x * 256 + threadIdx.x) * 8;
  int b = (int)(idx >> 21);  // C*L = 2^21
  int j = (int)(idx & (L_ - 1));
  float4 v0 = *(const float4*)(V + idx);
  float4 v1 = *(const float4*)(V + idx + 4);
  const float* m = mask + (size_t)b * L_ + j;
  float4 m0 = *(const float4*)m;
  float4 m1 = *(const float4*)(m + 4);
  uint4 o;
  o.x = pack_rne(v0.x * m0.x, v0.y * m0.y);
  o.y = pack_rne(v0.z * m0.z, v0.w * m0.w);
  o.z = pack_rne(v1.x * m1.x, v1.y * m1.y);
  o.w = pack_rne(v1.z * m1.z, v1.w * m1.w);
  *(uint4*)(Vb + idx) = o;
}

// ---------------------------------------------------------------------------
// m97-style NT GEMM mainloop (both operands bf16, k-contiguous, async staged)
// ---------------------------------------------------------------------------
__device__ __forceinline__ void gemm_mainloop(
    const unsigned short* Ab, const unsigned short* Bb, int lda, int ldb,
    int Kdim, unsigned short* sA, unsigned short* sB, f32x4 acc[4][4]) {
  int t = threadIdx.x;
  int f0 = t * 8;
  int f1 = 2048 + t * 8;
  int r0 = f0 >> 5, q0 = f0 & 31;
  int r1 = f1 >> 5, q1 = f1 & 31;
  const unsigned short* pA0 = Ab + (size_t)r0 * lda + q0;
  const unsigned short* pA1 = Ab + (size_t)r1 * lda + q1;
  const unsigned short* pB0 = Bb + (size_t)r0 * ldb + q0;
  const unsigned short* pB1 = Bb + (size_t)r1 * ldb + q1;
  int lane = t & 63;
  int quad = lane >> 4;
  int l15 = lane & 15;
  int w = t >> 6;
  int wm = (w & 1) * 64;
  int wn = (w >> 1) * 64;
  for (int kk = 0; kk < Kdim; kk += 32) {
    __syncthreads();
    g2lds16(pA0 + kk, sA + f0);
    g2lds16(pA1 + kk, sA + f1);
    g2lds16(pB0 + kk, sB + f0);
    g2lds16(pB1 + kk, sB + f1);
    __syncthreads();
    bf16x8 aF[4], bF[4];
#pragma unroll
    for (int ti = 0; ti < 4; ++ti)
      aF[ti] = *(const bf16x8*)(sA + (wm + ti * 16 + l15) * 32 + quad * 8);
#pragma unroll
    for (int tj = 0; tj < 4; ++tj)
      bF[tj] = *(const bf16x8*)(sB + (wn + tj * 16 + l15) * 32 + quad * 8);
#pragma unroll
    for (int ti = 0; ti < 4; ++ti)
#pragma unroll
      for (int tj = 0; tj < 4; ++tj)
        acc[ti][tj] = __builtin_amdgcn_mfma_f32_16x16x32_bf16(
            aF[ti], bF[tj], acc[ti][tj], 0, 0, 0);
  }
}

// ===========================================================================
// FAST PATH (ws_size large enough): t stored as bf16 (mask folded).
// tb region placement (tb[b] = L*L bf16 = half an attn batch slot):
//   tb0 -> attn slot 2 (first half), tb1 -> attn slot 3 (first half),
//   tb2 -> attn slot 3 (second half), tb3 -> workspace.
// finalize order 0,1,2,3: each batch's writes only clobber dead tb regions.
// ===========================================================================

// K1-fast: E = Qt*Kt^T; tv = exp(E*scale + log(mask+1e-6));
// tb = bf16(tv*mask); fp32 rowsum atomics (from unmasked tv).
__global__ __launch_bounds__(256) void gemm1_bf_k(
    const unsigned short* __restrict__ Qt, const unsigned short* __restrict__ Kt,
    const float* __restrict__ mask, unsigned short* __restrict__ t0,
    unsigned short* __restrict__ t1, unsigned short* __restrict__ t2,
    unsigned short* __restrict__ t3, float* __restrict__ rowsum) {
  int b = blockIdx.z;
  unsigned short* tbb = (b == 0) ? t0 : (b == 1) ? t1 : (b == 2) ? t2 : t3;
  int i0 = blockIdx.y * 128;
  int j0 = blockIdx.x * 128;
  __shared__ unsigned short sA[128 * 32];
  __shared__ unsigned short sB[128 * 32];
  f32x4 acc[4][4] = {};
  gemm_mainloop(Qt + (size_t)b * L_ * C_ + (size_t)i0 * C_,
                Kt + (size_t)b * L_ * C_ + (size_t)j0 * C_, C_, C_, C_, sA, sB,
                acc);
  int t = threadIdx.x;
  int lane = t & 63;
  int quad = lane >> 4;
  int l15 = lane & 15;
  int w = t >> 6;
  int wm = (w & 1) * 64;
  int wn = (w >> 1) * 64;
  const float scale = 0.04419417382415922f;  // 1/sqrt(512)
  float lm[4], mv[4];
#pragma unroll
  for (int tj = 0; tj < 4; ++tj) {
    int j = j0 + wn + tj * 16 + l15;
    float m = mask[(size_t)b * L_ + j];
    mv[tj] = m;
    lm[tj] = __logf(m + 1e-6f);
  }
  float rs[16];
#pragma unroll
  for (int q = 0; q < 16; ++q) rs[q] = 0.f;
#pragma unroll
  for (int ti = 0; ti < 4; ++ti) {
    int irow = i0 + wm + ti * 16 + quad * 4;  // C/D: row = quad*4 + reg
#pragma unroll
    for (int r = 0; r < 4; ++r) {
      size_t ro = (size_t)(irow + r) * L_;
#pragma unroll
      for (int tj = 0; tj < 4; ++tj) {
        float x = fminf(acc[ti][tj][r] * scale + lm[tj], 60.f);
        float tv = __expf(x);  // |logit| small: max-free softmax is safe
        rs[ti * 4 + r] += tv;
        tbb[ro + j0 + wn + tj * 16 + l15] = f2bf_rne(tv * mv[tj]);
      }
    }
  }
#pragma unroll
  for (int m = 1; m < 16; m <<= 1)
#pragma unroll
    for (int q = 0; q < 16; ++q) rs[q] += __shfl_xor(rs[q], m, 64);
  if (l15 == 0) {
    float* rb = rowsum + (size_t)b * L_ + i0 + wm;
#pragma unroll
    for (int ti = 0; ti < 4; ++ti)
#pragma unroll
      for (int r = 0; r < 4; ++r)
        atomicAdd(&rb[ti * 16 + quad * 4 + r], rs[ti * 4 + r]);
  }
}

// K2-fast: out[c,i] += inv[i]*sum_j Vb[c,j]*tb[i,j].  Both operands bf16,
// pure async mainloop.  split-K=2 over j for occupancy -> atomicAdd epilogue.
// grid (L/128, C/128, B*2): z = b + 4*ks
__global__ __launch_bounds__(256) void gemm2_bf_k(
    const unsigned short* __restrict__ Vb, const unsigned short* __restrict__ t0,
    const unsigned short* __restrict__ t1, const unsigned short* __restrict__ t2,
    const unsigned short* __restrict__ t3, const float* __restrict__ rowsum,
    float* __restrict__ out) {
  int z = blockIdx.z;
  int b = z & 3;
  int ks = z >> 2;
  const unsigned short* tbb =
      (b == 0) ? t0 : (b == 1) ? t1 : (b == 2) ? t2 : t3;
  int c0 = blockIdx.y * 128;
  int i0 = blockIdx.x * 128;
  __shared__ unsigned short sA[128 * 32];
  __shared__ unsigned short sB[128 * 32];
  f32x4 acc[4][4] = {};
  gemm_mainloop(Vb + (size_t)b * C_ * L_ + (size_t)c0 * L_ + ks * (L_ / 2),
                tbb + (size_t)i0 * L_ + ks * (L_ / 2), L_, L_, L_ / 2, sA, sB,
                acc);
  int t = threadIdx.x;
  int lane = t & 63;
  int quad = lane >> 4;
  int l15 = lane & 15;
  int w = t >> 6;
  int wm = (w & 1) * 64;
  int wn = (w >> 1) * 64;
  float invv[4];
#pragma unroll
  for (int tj = 0; tj < 4; ++tj)
    invv[tj] = 1.0f / rowsum[(size_t)b * L_ + i0 + wn + tj * 16 + l15];
  float* ob = out + (size_t)b * C_ * L_;
#pragma unroll
  for (int ti = 0; ti < 4; ++ti) {
    int crow = c0 + wm + ti * 16 + quad * 4;
#pragma unroll
    for (int r = 0; r < 4; ++r) {
      size_t ro = (size_t)(crow + r) * L_;
#pragma unroll
      for (int tj = 0; tj < 4; ++tj)
        atomicAdd(&ob[ro + i0 + wn + tj * 16 + l15],
                  acc[ti][tj][r] * invv[tj]);
    }
  }
}

// K3-fast: dst[j,i] = bf2f(src[i,j]) / rowsum[i]  (out-of-place, per batch).
// grid (64, 64), block 256.
__global__ __launch_bounds__(256) void finalize_k(
    const unsigned short* __restrict__ src, const float* __restrict__ rs,
    float* __restrict__ dst) {
  int jt = blockIdx.x, it = blockIdx.y;
  __shared__ float tileT[64][65];
  int t = threadIdx.x;
  int r = t >> 2, cg = (t & 3) * 16;
  int i = it * 64 + r;
  float inv = 1.0f / rs[i];
  const unsigned short* sp = src + (size_t)i * L_ + jt * 64 + cg;
  uint4 u0 = *(const uint4*)sp;
  uint4 u1 = *(const uint4*)(sp + 8);
  const unsigned* w0 = (const unsigned*)&u0;
  const unsigned* w1 = (const unsigned*)&u1;
#pragma unroll
  for (int k = 0; k < 4; ++k) {
    tileT[cg + 2 * k + 0][r] = bflo2f(w0[k]) * inv;
    tileT[cg + 2 * k + 1][r] = bfhi2f(w0[k]) * inv;
    tileT[cg + 8 + 2 * k + 0][r] = bflo2f(w1[k]) * inv;
    tileT[cg + 8 + 2 * k + 1][r] = bfhi2f(w1[k]) * inv;
  }
  __syncthreads();
  float* dp = dst + (size_t)(jt * 64 + r) * L_ + it * 64 + cg;
#pragma unroll
  for (int q = 0; q < 4; ++q) {
    float4 o;
    o.x = tileT[r][cg + 4 * q + 0];
    o.y = tileT[r][cg + 4 * q + 1];
    o.z = tileT[r][cg + 4 * q + 2];
    o.w = tileT[r][cg + 4 * q + 3];
    *(float4*)(dp + 4 * q) = o;
  }
}

// ===========================================================================
// FALLBACK PATH (small ws): exact previous pipeline, known-good at 813 us.
// ===========================================================================
__global__ __launch_bounds__(256) void gemm1_k(
    const unsigned short* __restrict__ Qt, const unsigned short* __restrict__ Kt,
    const float* __restrict__ mask, float* __restrict__ attn,
    float* __restrict__ rowsum) {
  int b = blockIdx.z;
  int i0 = blockIdx.y * 128;
  int j0 = blockIdx.x * 128;
  __shared__ unsigned short sA[128 * 32];
  __shared__ unsigned short sB[128 * 32];
  f32x4 acc[4][4] = {};
  gemm_mainloop(Qt + (size_t)b * L_ * C_ + (size_t)i0 * C_,
                Kt + (size_t)b * L_ * C_ + (size_t)j0 * C_, C_, C_, C_, sA, sB,
                acc);
  int t = threadIdx.x;
  int lane = t & 63;
  int quad = lane >> 4;
  int l15 = lane & 15;
  int w = t >> 6;
  int wm = (w & 1) * 64;
  int wn = (w >> 1) * 64;
  const float scale = 0.04419417382415922f;
  float lm[4];
#pragma unroll
  for (int tj = 0; tj < 4; ++tj) {
    int j = j0 + wn + tj * 16 + l15;
    lm[tj] = __logf(mask[(size_t)b * L_ + j] + 1e-6f);
  }
  float* ab = attn + (size_t)b * L_ * L_;
  float rs[16];
#pragma unroll
  for (int q = 0; q < 16; ++q) rs[q] = 0.f;
#pragma unroll
  for (int ti = 0; ti < 4; ++ti) {
    int irow = i0 + wm + ti * 16 + quad * 4;
#pragma unroll
    for (int r = 0; r < 4; ++r) {
      size_t ro = (size_t)(irow + r) * L_;
#pragma unroll
      for (int tj = 0; tj < 4; ++tj) {
        float x = fminf(acc[ti][tj][r] * scale + lm[tj], 60.f);
        float tv = __expf(x);
        rs[ti * 4 + r] += tv;
        ab[ro + j0 + wn + tj * 16 + l15] = tv;
      }
    }
  }
#pragma unroll
  for (int m = 1; m < 16; m <<= 1)
#pragma unroll
    for (int q = 0; q < 16; ++q) rs[q] += __shfl_xor(rs[q], m, 64);
  if (l15 == 0) {
    float* rb = rowsum + (size_t)b * L_ + i0 + wm;
#pragma unroll
    for (int ti = 0; ti < 4; ++ti)
#pragma unroll
      for (int r = 0; r < 4; ++r)
        atomicAdd(&rb[ti * 16 + quad * 4 + r], rs[ti * 4 + r]);
  }
}

__global__ __launch_bounds__(256) void gemm2_k(
    const unsigned short* __restrict__ Vb, const float* __restrict__ tmat,
    const float* __restrict__ rowsum, float* __restrict__ out) {
  int b = blockIdx.z;
  int c0 = blockIdx.y * 128;
  int i0 = blockIdx.x * 128;
  __shared__ unsigned short sA[128 * 32];
  __shared__ unsigned short sB[128 * 32];
  const unsigned short* Ab = Vb + (size_t)b * C_ * L_ + (size_t)c0 * L_;
  const float* Bb = tmat + (size_t)b * L_ * L_ + (size_t)i0 * L_;
  int t = threadIdx.x;
  int f0 = t * 8;
  int f1 = 2048 + t * 8;
  int r0 = f0 >> 5, q0 = f0 & 31;
  int r1 = f1 >> 5, q1 = f1 & 31;
  const unsigned short* pA0 = Ab + (size_t)r0 * L_ + q0;
  const unsigned short* pA1 = Ab + (size_t)r1 * L_ + q1;
  const float* pB0 = Bb + (size_t)r0 * L_ + q0;
  const float* pB1 = Bb + (size_t)r1 * L_ + q1;
  int lane = t & 63;
  int quad = lane >> 4;
  int l15 = lane & 15;
  int w = t >> 6;
  int wm = (w & 1) * 64;
  int wn = (w >> 1) * 64;
  f32x4 acc[4][4] = {};
  for (int kk = 0; kk < L_; kk += 32) {
    __syncthreads();
    g2lds16(pA0 + kk, sA + f0);
    g2lds16(pA1 + kk, sA + f1);
    float4 x0 = *(const float4*)(pB0 + kk);
    float4 x1 = *(const float4*)(pB0 + kk + 4);
    float4 y0 = *(const float4*)(pB1 + kk);
    float4 y1 = *(const float4*)(pB1 + kk + 4);
    uint4 u0, u1;
    u0.x = pack_trunc(x0.x, x0.y); u0.y = pack_trunc(x0.z, x0.w);
    u0.z = pack_trunc(x1.x, x1.y); u0.w = pack_trunc(x1.z, x1.w);
    u1.x = pack_trunc(y0.x, y0.y); u1.y = pack_trunc(y0.z, y0.w);
    u1.z = pack_trunc(y1.x, y1.y); u1.w = pack_trunc(y1.z, y1.w);
    *(uint4*)(sB + f0) = u0;
    *(uint4*)(sB + f1) = u1;
    __syncthreads();
    bf16x8 aF[4], bF[4];
#pragma unroll
    for (int ti = 0; ti < 4; ++ti)
      aF[ti] = *(const bf16x8*)(sA + (wm + ti * 16 + l15) * 32 + quad * 8);
#pragma unroll
    for (int tj = 0; tj < 4; ++tj)
      bF[tj] = *(const bf16x8*)(sB + (wn + tj * 16 + l15) * 32 + quad * 8);
#pragma unroll
    for (int ti = 0; ti < 4; ++ti)
#pragma unroll
      for (int tj = 0; tj < 4; ++tj)
        acc[ti][tj] = __builtin_amdgcn_mfma_f32_16x16x32_bf16(
            aF[ti], bF[tj], acc[ti][tj], 0, 0, 0);
  }
  float invv[4];
#pragma unroll
  for (int tj = 0; tj < 4; ++tj)
    invv[tj] = 1.0f / rowsum[(size_t)b * L_ + i0 + wn + tj * 16 + l15];
  float* ob = out + (size_t)b * C_ * L_;
#pragma unroll
  for (int ti = 0; ti < 4; ++ti) {
    int crow = c0 + wm + ti * 16 + quad * 4;
#pragma unroll
    for (int r = 0; r < 4; ++r) {
      size_t ro = (size_t)(crow + r) * L_;
#pragma unroll
      for (int tj = 0; tj < 4; ++tj)
        ob[ro + i0 + wn + tj * 16 + l15] = acc[ti][tj][r] * invv[tj];
    }
  }
}

__global__ __launch_bounds__(256) void transpose_scale_k(
    float* __restrict__ attn, const float* __restrict__ rowsum,
    const float* __restrict__ mask) {
  int ti = blockIdx.x, tj = blockIdx.y;
  if (ti > tj) return;
  int b = blockIdx.z;
  float* M = attn + (size_t)b * L_ * L_;
  const float* mk = mask + (size_t)b * L_;
  const float* rs = rowsum + (size_t)b * L_;
  __shared__ float t1[64][65];
  __shared__ float t2[64][65];
  int t = threadIdx.x;
  int r = t >> 2, cg = (t & 3) * 16;
  bool diag = (ti == tj);
  {
    const float* xp = M + (size_t)(ti * 64 + r) * L_ + tj * 64 + cg;
    float invx = 1.0f / rs[ti * 64 + r];
    const float* mx = mk + tj * 64 + cg;
#pragma unroll
    for (int q = 0; q < 4; ++q) {
      float4 v = *(const float4*)(xp + 4 * q);
      float4 m = *(const float4*)(mx + 4 * q);
      t1[r][cg + 4 * q + 0] = v.x * m.x * invx;
      t1[r][cg + 4 * q + 1] = v.y * m.y * invx;
      t1[r][cg + 4 * q + 2] = v.z * m.z * invx;
      t1[r][cg + 4 * q + 3] = v.w * m.w * invx;
    }
  }
  if (!diag) {
    const float* yp = M + (size_t)(tj * 64 + r) * L_ + ti * 64 + cg;
    float invy = 1.0f / rs[tj * 64 + r];
    const float* my = mk + ti * 64 + cg;
#pragma unroll
    for (int q = 0; q < 4; ++q) {
      float4 v = *(const float4*)(yp + 4 * q);
      float4 m = *(const float4*)(my + 4 * q);
      t2[r][cg + 4 * q + 0] = v.x * m.x * invy;
      t2[r][cg + 4 * q + 1] = v.y * m.y * invy;
      t2[r][cg + 4 * q + 2] = v.z * m.z * invy;
      t2[r][cg + 4 * q + 3] = v.w * m.w * invy;
    }
  }
  __syncthreads();
  {
    float* dp = M + (size_t)(tj * 64 + r) * L_ + ti * 64 + cg;
#pragma unroll
    for (int q = 0; q < 4; ++q) {
      float4 o;
      o.x = t1[cg + 4 * q + 0][r];
      o.y = t1[cg + 4 * q + 1][r];
      o.z = t1[cg + 4 * q + 2][r];
      o.w = t1[cg + 4 * q + 3][r];
      *(float4*)(dp + 4 * q) = o;
    }
  }
  if (!diag) {
    float* dp = M + (size_t)(ti * 64 + r) * L_ + tj * 64 + cg;
#pragma unroll
    for (int q = 0; q < 4; ++q) {
      float4 o;
      o.x = t2[cg + 4 * q + 0][r];
      o.y = t2[cg + 4 * q + 1][r];
      o.z = t2[cg + 4 * q + 2][r];
      o.w = t2[cg + 4 * q + 3][r];
      *(float4*)(dp + 4 * q) = o;
    }
  }
}

extern "C" void kernel_launch(void* const* d_in, const int* in_sizes, int n_in,
                              void* d_out, int out_size, void* d_ws,
                              size_t ws_size, hipStream_t stream) {
  const float* Q = (const float*)d_in[0];
  const float* K = (const float*)d_in[1];
  const float* V = (const float*)d_in[2];
  const float* mask = (const float*)d_in[3];

  float* out = (float*)d_out;                // (B,C,L) fp32
  float* attn = out + (size_t)B_ * C_ * L_;  // (B,L,L) fp32

  const size_t NQ = (size_t)B_ * L_ * C_;  // elems per bf16 tensor
  unsigned short* Qt = (unsigned short*)d_ws;
  unsigned short* Kt = Qt + NQ;
  unsigned short* Vb = Kt + NQ;
  float* rowsum = (float*)(Vb + NQ);
  unsigned short* tb3 = (unsigned short*)(rowsum + (size_t)B_ * L_);

  const size_t need = NQ * 2 * 3 + (size_t)B_ * L_ * 4 + (size_t)L_ * L_ * 2;

  hipMemsetAsync(rowsum, 0, (size_t)B_ * L_ * sizeof(float), stream);
  transpose_cast_k<<<dim3(L_ / 64, C_ / 64, B_ * 2), 256, 0, stream>>>(Q, K, Qt,
                                                                       Kt);
  cast_v_k<<<dim3((B_ * C_ * L_) / 2048), 256, 0, stream>>>(V, mask, Vb);

  if (ws_size >= need) {
    // bf16-t fast path.  tb0..tb2 parked in not-yet-final attn slots.
    const size_t SLOT = (size_t)L_ * L_;  // floats per attn batch slot
    unsigned short* tb0 = (unsigned short*)(attn + 2 * SLOT);
    unsigned short* tb1 = (unsigned short*)(attn + 3 * SLOT);
    unsigned short* tb2 = (unsigned short*)(attn + 3 * SLOT + SLOT / 2);
    hipMemsetAsync(out, 0, (size_t)B_ * C_ * L_ * sizeof(float), stream);
    gemm1_bf_k<<<dim3(L_ / 128, L_ / 128, B_), 256, 0, stream>>>(
        Qt, Kt, mask, tb0, tb1, tb2, tb3, rowsum);
    gemm2_bf_k<<<dim3(L_ / 128, C_ / 128, B_ * 2), 256, 0, stream>>>(
        Vb, tb0, tb1, tb2, tb3, rowsum, out);
    // finalize order 0,1,2,3: writes of batch b only clobber dead tb regions
    finalize_k<<<dim3(64, 64), 256, 0, stream>>>(tb0, rowsum, attn);
    finalize_k<<<dim3(64, 64), 256, 0, stream>>>(tb1, rowsum + L_,
                                                 attn + 1 * SLOT);
    finalize_k<<<dim3(64, 64), 256, 0, stream>>>(tb2, rowsum + 2 * L_,
                                                 attn + 2 * SLOT);
    finalize_k<<<dim3(64, 64), 256, 0, stream>>>(tb3, rowsum + 3 * L_,
                                                 attn + 3 * SLOT);
  } else {
    // fallback: previous known-good fp32-t pipeline
    gemm1_k<<<dim3(L_ / 128, L_ / 128, B_), 256, 0, stream>>>(Qt, Kt, mask,
                                                              attn, rowsum);
    gemm2_k<<<dim3(L_ / 128, C_ / 128, B_), 256, 0, stream>>>(Vb, attn, rowsum,
                                                              out);
    transpose_scale_k<<<dim3(64, 64, B_), 256, 0, stream>>>(attn, rowsum,
                                                            mask);
  }
}

// Round 2
// 668.720 us; speedup vs baseline: 1.2157x; 1.0764x over previous
//
#include <hip/hip_runtime.h>

#define B_ 4
#define C_ 512
#define L_ 4096

typedef __attribute__((ext_vector_type(8))) short bf16x8;
typedef __attribute__((ext_vector_type(4))) float f32x4;

static __device__ __forceinline__ unsigned short f2bf_rne(float f) {
  unsigned u = __float_as_uint(f);
  u += 0x7FFFu + ((u >> 16) & 1u);  // round-to-nearest-even
  return (unsigned short)(u >> 16);
}
static __device__ __forceinline__ unsigned pack_rne(float a, float b) {
  return (unsigned)f2bf_rne(a) | ((unsigned)f2bf_rne(b) << 16);
}
static __device__ __forceinline__ float bflo2f(unsigned w) {
  return __uint_as_float(w << 16);
}
static __device__ __forceinline__ float bfhi2f(unsigned w) {
  return __uint_as_float(w & 0xFFFF0000u);
}

// async global -> LDS, 16 B/lane; LDS dest = wave-uniform base + lane*16.
static __device__ __forceinline__ void g2lds16(const unsigned short* g,
                                               unsigned short* l) {
  __builtin_amdgcn_global_load_lds(
      (const __attribute__((address_space(1))) unsigned int*)g,
      (__attribute__((address_space(3))) unsigned int*)l, 16, 0, 0);
}

// ---------------------------------------------------------------------------
// K0: Q,K fp32 (C,L) -> Qt,Kt bf16 (L,C).  grid (L/64, C/64, B*2), block 256
// ---------------------------------------------------------------------------
__global__ __launch_bounds__(256) void transpose_cast_k(
    const float* __restrict__ Q, const float* __restrict__ K,
    unsigned short* __restrict__ Qt, unsigned short* __restrict__ Kt) {
  int zb = blockIdx.z;
  int b = zb >> 1;
  const float* src = ((zb & 1) ? K : Q) + (size_t)b * C_ * L_;
  unsigned short* dst = ((zb & 1) ? Kt : Qt) + (size_t)b * L_ * C_;
  int i0 = blockIdx.x * 64, c0 = blockIdx.y * 64;
  __shared__ float tile[64][65];
  int t = threadIdx.x;
  int cr = t >> 2, ig = (t & 3) * 16;
  const float* s = src + (size_t)(c0 + cr) * L_ + i0 + ig;
#pragma unroll
  for (int q = 0; q < 4; ++q) {
    float4 v = *(const float4*)(s + 4 * q);
    tile[cr][ig + 4 * q + 0] = v.x;
    tile[cr][ig + 4 * q + 1] = v.y;
    tile[cr][ig + 4 * q + 2] = v.z;
    tile[cr][ig + 4 * q + 3] = v.w;
  }
  __syncthreads();
  int ir = t >> 2, cg = (t & 3) * 16;
  unsigned wds[8];
#pragma unroll
  for (int k = 0; k < 8; ++k)
    wds[k] = pack_rne(tile[cg + 2 * k][ir], tile[cg + 2 * k + 1][ir]);
  unsigned short* d = dst + (size_t)(i0 + ir) * C_ + c0 + cg;
  uint4 o0, o1;
  o0.x = wds[0]; o0.y = wds[1]; o0.z = wds[2]; o0.w = wds[3];
  o1.x = wds[4]; o1.y = wds[5]; o1.z = wds[6]; o1.w = wds[7];
  *(uint4*)d = o0;
  *(uint4*)(d + 8) = o1;
}

// ---------------------------------------------------------------------------
// K0b: Vb[b,c,j] = bf16(V[b,c,j] * mask[b,j])
// ---------------------------------------------------------------------------
__global__ __launch_bounds__(256) void cast_v_k(
    const float* __restrict__ V, const float* __restrict__ mask,
    unsigned short* __restrict__ Vb) {
  size_t idx = ((size_t)blockIdx.x * 256 + threadIdx.x) * 8;
  int b = (int)(idx >> 21);  // C*L = 2^21
  int j = (int)(idx & (L_ - 1));
  float4 v0 = *(const float4*)(V + idx);
  float4 v1 = *(const float4*)(V + idx + 4);
  const float* m = mask + (size_t)b * L_ + j;
  float4 m0 = *(const float4*)m;
  float4 m1 = *(const float4*)(m + 4);
  uint4 o;
  o.x = pack_rne(v0.x * m0.x, v0.y * m0.y);
  o.y = pack_rne(v0.z * m0.z, v0.w * m0.w);
  o.z = pack_rne(v1.x * m1.x, v1.y * m1.y);
  o.w = pack_rne(v1.z * m1.z, v1.w * m1.w);
  *(uint4*)(Vb + idx) = o;
}

// ---------------------------------------------------------------------------
// NT GEMM mainloop, BK=64, sub-tiled LDS [2 kc][128 rows][32 k] per operand
// (16 KB each).  Fragment addressing within each kc region is identical to
// the BK=32 layout -> same bank behavior, same summation order; but only
// one barrier-pair per 64 k (half the drains).
// ---------------------------------------------------------------------------
__device__ __forceinline__ void gemm_mainloop64(
    const unsigned short* Ab, const unsigned short* Bb, int lda, int ldb,
    int Kdim, unsigned short* sA, unsigned short* sB, f32x4 acc[4][4]) {
  int t = threadIdx.x;
  const unsigned short* pA[4];
  const unsigned short* pB[4];
#pragma unroll
  for (int c = 0; c < 4; ++c) {
    int e = t * 8 + c * 2048;  // LDS elem index (0..8191)
    int kc = e >> 12;          // 4096 elems per kc region
    int rem = e & 4095;
    int row = rem >> 5;        // 32 elems per row-half
    int col = rem & 31;
    int off = kc * 32 + col;   // elem offset within the 64-wide k tile
    pA[c] = Ab + (size_t)row * lda + off;
    pB[c] = Bb + (size_t)row * ldb + off;
  }
  int lane = t & 63;
  int quad = lane >> 4;
  int l15 = lane & 15;
  int w = t >> 6;
  int wm = (w & 1) * 64;
  int wn = (w >> 1) * 64;
  for (int kk = 0; kk < Kdim; kk += 64) {
    __syncthreads();
#pragma unroll
    for (int c = 0; c < 4; ++c) g2lds16(pA[c] + kk, sA + t * 8 + c * 2048);
#pragma unroll
    for (int c = 0; c < 4; ++c) g2lds16(pB[c] + kk, sB + t * 8 + c * 2048);
    __syncthreads();
#pragma unroll
    for (int kc = 0; kc < 2; ++kc) {
      bf16x8 aF[4], bF[4];
#pragma unroll
      for (int ti = 0; ti < 4; ++ti)
        aF[ti] = *(const bf16x8*)(sA + kc * 4096 +
                                  (wm + ti * 16 + l15) * 32 + quad * 8);
#pragma unroll
      for (int tj = 0; tj < 4; ++tj)
        bF[tj] = *(const bf16x8*)(sB + kc * 4096 +
                                  (wn + tj * 16 + l15) * 32 + quad * 8);
#pragma unroll
      for (int ti = 0; ti < 4; ++ti)
#pragma unroll
        for (int tj = 0; tj < 4; ++tj)
          acc[ti][tj] = __builtin_amdgcn_mfma_f32_16x16x32_bf16(
              aF[ti], bF[tj], acc[ti][tj], 0, 0, 0);
    }
  }
}

// ---------------------------------------------------------------------------
// K1: E = Qt*Kt^T; tv = exp(E*scale + log(mask+1e-6));
// tb = bf16(tv*mask); fp32 rowsum atomics.  grid (L/128, L/128, B)
// ---------------------------------------------------------------------------
__global__ __launch_bounds__(256) void gemm1_bf_k(
    const unsigned short* __restrict__ Qt, const unsigned short* __restrict__ Kt,
    const float* __restrict__ mask, unsigned short* __restrict__ t0,
    unsigned short* __restrict__ t1, unsigned short* __restrict__ t2,
    unsigned short* __restrict__ t3, float* __restrict__ rowsum) {
  int b = blockIdx.z;
  unsigned short* tbb = (b == 0) ? t0 : (b == 1) ? t1 : (b == 2) ? t2 : t3;
  int i0 = blockIdx.y * 128;
  int j0 = blockIdx.x * 128;
  __shared__ unsigned short sA[8192];
  __shared__ unsigned short sB[8192];
  f32x4 acc[4][4] = {};
  gemm_mainloop64(Qt + (size_t)b * L_ * C_ + (size_t)i0 * C_,
                  Kt + (size_t)b * L_ * C_ + (size_t)j0 * C_, C_, C_, C_, sA,
                  sB, acc);
  int t = threadIdx.x;
  int lane = t & 63;
  int quad = lane >> 4;
  int l15 = lane & 15;
  int w = t >> 6;
  int wm = (w & 1) * 64;
  int wn = (w >> 1) * 64;
  const float scale = 0.04419417382415922f;  // 1/sqrt(512)
  float lm[4], mv[4];
#pragma unroll
  for (int tj = 0; tj < 4; ++tj) {
    int j = j0 + wn + tj * 16 + l15;
    float m = mask[(size_t)b * L_ + j];
    mv[tj] = m;
    lm[tj] = __logf(m + 1e-6f);
  }
  float rs[16];
#pragma unroll
  for (int q = 0; q < 16; ++q) rs[q] = 0.f;
#pragma unroll
  for (int ti = 0; ti < 4; ++ti) {
    int irow = i0 + wm + ti * 16 + quad * 4;  // C/D: row = quad*4 + reg
#pragma unroll
    for (int r = 0; r < 4; ++r) {
      size_t ro = (size_t)(irow + r) * L_;
#pragma unroll
      for (int tj = 0; tj < 4; ++tj) {
        float x = fminf(acc[ti][tj][r] * scale + lm[tj], 60.f);
        float tv = __expf(x);  // |logit| small: max-free softmax is safe
        rs[ti * 4 + r] += tv;
        tbb[ro + j0 + wn + tj * 16 + l15] = f2bf_rne(tv * mv[tj]);
      }
    }
  }
#pragma unroll
  for (int m = 1; m < 16; m <<= 1)
#pragma unroll
    for (int q = 0; q < 16; ++q) rs[q] += __shfl_xor(rs[q], m, 64);
  if (l15 == 0) {
    float* rb = rowsum + (size_t)b * L_ + i0 + wm;
#pragma unroll
    for (int ti = 0; ti < 4; ++ti)
#pragma unroll
      for (int r = 0; r < 4; ++r)
        atomicAdd(&rb[ti * 16 + quad * 4 + r], rs[ti * 4 + r]);
  }
}

// ---------------------------------------------------------------------------
// K2: out[c,i] (+)= inv[i]*sum_j Vb[c,j]*tb[i,j].  split-K=2 over j.
// ATOMIC=true: atomicAdd into zeroed out.  ATOMIC=false: ks=0 stores to out,
// ks=1 stores to out2 (combined later).  grid (L/128, C/128, B*2)
// ---------------------------------------------------------------------------
template <bool ATOMIC>
__global__ __launch_bounds__(256) void gemm2_bf_k(
    const unsigned short* __restrict__ Vb, const unsigned short* __restrict__ t0,
    const unsigned short* __restrict__ t1, const unsigned short* __restrict__ t2,
    const unsigned short* __restrict__ t3, const float* __restrict__ rowsum,
    float* __restrict__ out, float* __restrict__ out2) {
  int z = blockIdx.z;
  int b = z & 3;
  int ks = z >> 2;
  const unsigned short* tbb =
      (b == 0) ? t0 : (b == 1) ? t1 : (b == 2) ? t2 : t3;
  int c0 = blockIdx.y * 128;
  int i0 = blockIdx.x * 128;
  __shared__ unsigned short sA[8192];
  __shared__ unsigned short sB[8192];
  f32x4 acc[4][4] = {};
  gemm_mainloop64(Vb + (size_t)b * C_ * L_ + (size_t)c0 * L_ + ks * (L_ / 2),
                  tbb + (size_t)i0 * L_ + ks * (L_ / 2), L_, L_, L_ / 2, sA, sB,
                  acc);
  int t = threadIdx.x;
  int lane = t & 63;
  int quad = lane >> 4;
  int l15 = lane & 15;
  int w = t >> 6;
  int wm = (w & 1) * 64;
  int wn = (w >> 1) * 64;
  float invv[4];
#pragma unroll
  for (int tj = 0; tj < 4; ++tj)
    invv[tj] = 1.0f / rowsum[(size_t)b * L_ + i0 + wn + tj * 16 + l15];
  float* ob = (ATOMIC ? out : (ks ? out2 : out)) + (size_t)b * C_ * L_;
#pragma unroll
  for (int ti = 0; ti < 4; ++ti) {
    int crow = c0 + wm + ti * 16 + quad * 4;
#pragma unroll
    for (int r = 0; r < 4; ++r) {
      size_t ro = (size_t)(crow + r) * L_;
#pragma unroll
      for (int tj = 0; tj < 4; ++tj) {
        float v = acc[ti][tj][r] * invv[tj];
        if (ATOMIC)
          atomicAdd(&ob[ro + i0 + wn + tj * 16 + l15], v);
        else
          ob[ro + i0 + wn + tj * 16 + l15] = v;
      }
    }
  }
}

// ---------------------------------------------------------------------------
// K2b: out += out2  (split-K combine).  grid (B*C*L)/2048, block 256.
// ---------------------------------------------------------------------------
__global__ __launch_bounds__(256) void combine_out_k(
    float* __restrict__ out, const float* __restrict__ out2) {
  size_t idx = ((size_t)blockIdx.x * 256 + threadIdx.x) * 8;
  float4 a0 = *(const float4*)(out + idx);
  float4 a1 = *(const float4*)(out + idx + 4);
  float4 b0 = *(const float4*)(out2 + idx);
  float4 b1 = *(const float4*)(out2 + idx + 4);
  a0.x += b0.x; a0.y += b0.y; a0.z += b0.z; a0.w += b0.w;
  a1.x += b1.x; a1.y += b1.y; a1.z += b1.z; a1.w += b1.w;
  *(float4*)(out + idx) = a0;
  *(float4*)(out + idx + 4) = a1;
}

// ---------------------------------------------------------------------------
// K3: attn[b][j,i] = bf2f(tb[b][i,j]) / rowsum[b][i]   (out-of-place).
// grid (64, 64, nb), block 256.  For nb>1, tb/attn must not alias.
// ---------------------------------------------------------------------------
__global__ __launch_bounds__(256) void finalize_all_k(
    const unsigned short* __restrict__ tb, const float* __restrict__ rowsum,
    float* __restrict__ attn) {
  int b = blockIdx.z;
  const unsigned short* src = tb + (size_t)b * L_ * L_;
  const float* rs = rowsum + (size_t)b * L_;
  float* dst = attn + (size_t)b * L_ * L_;
  int jt = blockIdx.x, it = blockIdx.y;
  __shared__ float tileT[64][65];
  int t = threadIdx.x;
  int r = t >> 2, cg = (t & 3) * 16;
  int i = it * 64 + r;
  float inv = 1.0f / rs[i];
  const unsigned short* sp = src + (size_t)i * L_ + jt * 64 + cg;
  uint4 u0 = *(const uint4*)sp;
  uint4 u1 = *(const uint4*)(sp + 8);
  const unsigned* w0 = (const unsigned*)&u0;
  const unsigned* w1 = (const unsigned*)&u1;
#pragma unroll
  for (int k = 0; k < 4; ++k) {
    tileT[cg + 2 * k + 0][r] = bflo2f(w0[k]) * inv;
    tileT[cg + 2 * k + 1][r] = bfhi2f(w0[k]) * inv;
    tileT[cg + 8 + 2 * k + 0][r] = bflo2f(w1[k]) * inv;
    tileT[cg + 8 + 2 * k + 1][r] = bfhi2f(w1[k]) * inv;
  }
  __syncthreads();
  float* dp = dst + (size_t)(jt * 64 + r) * L_ + it * 64 + cg;
#pragma unroll
  for (int q = 0; q < 4; ++q) {
    float4 o;
    o.x = tileT[r][cg + 4 * q + 0];
    o.y = tileT[r][cg + 4 * q + 1];
    o.z = tileT[r][cg + 4 * q + 2];
    o.w = tileT[r][cg + 4 * q + 3];
    *(float4*)(dp + 4 * q) = o;
  }
}

extern "C" void kernel_launch(void* const* d_in, const int* in_sizes, int n_in,
                              void* d_out, int out_size, void* d_ws,
                              size_t ws_size, hipStream_t stream) {
  const float* Q = (const float*)d_in[0];
  const float* K = (const float*)d_in[1];
  const float* V = (const float*)d_in[2];
  const float* mask = (const float*)d_in[3];

  float* out = (float*)d_out;                // (B,C,L) fp32
  float* attn = out + (size_t)B_ * C_ * L_;  // (B,L,L) fp32

  const size_t NQ = (size_t)B_ * L_ * C_;    // elems per bf16 operand tensor
  const size_t SLOT = (size_t)L_ * L_;       // elems per (L,L) matrix
  unsigned short* Qt = (unsigned short*)d_ws;
  unsigned short* Kt = Qt + NQ;
  unsigned short* Vb = Kt + NQ;
  float* rowsum = (float*)(Vb + NQ);
  unsigned short* wtail = (unsigned short*)(rowsum + (size_t)B_ * L_);

  // tier-1: tb (B,L,L) bf16 + out2 (B,C,L) fp32 all in dedicated workspace
  const size_t need1 =
      NQ * 2 * 3 + (size_t)B_ * L_ * 4 + (size_t)B_ * SLOT * 2 + NQ * 4;

  hipMemsetAsync(rowsum, 0, (size_t)B_ * L_ * sizeof(float), stream);
  transpose_cast_k<<<dim3(L_ / 64, C_ / 64, B_ * 2), 256, 0, stream>>>(Q, K, Qt,
                                                                       Kt);
  cast_v_k<<<dim3((B_ * C_ * L_) / 2048), 256, 0, stream>>>(V, mask, Vb);

  if (ws_size >= need1) {
    unsigned short* tb = wtail;                       // (B,L,L) bf16
    float* out2 = (float*)(tb + (size_t)B_ * SLOT);   // (B,C,L) fp32
    gemm1_bf_k<<<dim3(L_ / 128, L_ / 128, B_), 256, 0, stream>>>(
        Qt, Kt, mask, tb, tb + SLOT, tb + 2 * SLOT, tb + 3 * SLOT, rowsum);
    gemm2_bf_k<false><<<dim3(L_ / 128, C_ / 128, B_ * 2), 256, 0, stream>>>(
        Vb, tb, tb + SLOT, tb + 2 * SLOT, tb + 3 * SLOT, rowsum, out, out2);
    combine_out_k<<<dim3((B_ * C_ * L_) / 2048), 256, 0, stream>>>(out, out2);
    finalize_all_k<<<dim3(64, 64, B_), 256, 0, stream>>>(tb, rowsum, attn);
  } else {
    // fallback tier: tb parked in not-yet-final attn slots (round-1 layout).
    // finalize order 0,1,2,3 keeps clobbered tb regions dead.
    unsigned short* tb0 = (unsigned short*)(attn + 2 * SLOT);
    unsigned short* tb1 = (unsigned short*)(attn + 3 * SLOT);
    unsigned short* tb2 = (unsigned short*)(attn + 3 * SLOT + SLOT / 2);
    unsigned short* tb3 = wtail;
    hipMemsetAsync(out, 0, (size_t)B_ * C_ * L_ * sizeof(float), stream);
    gemm1_bf_k<<<dim3(L_ / 128, L_ / 128, B_), 256, 0, stream>>>(
        Qt, Kt, mask, tb0, tb1, tb2, tb3, rowsum);
    gemm2_bf_k<true><<<dim3(L_ / 128, C_ / 128, B_ * 2), 256, 0, stream>>>(
        Vb, tb0, tb1, tb2, tb3, rowsum, out, out);
    finalize_all_k<<<dim3(64, 64, 1), 256, 0, stream>>>(tb0, rowsum, attn);
    finalize_all_k<<<dim3(64, 64, 1), 256, 0, stream>>>(tb1, rowsum + L_,
                                                        attn + SLOT);
    finalize_all_k<<<dim3(64, 64, 1), 256, 0, stream>>>(tb2, rowsum + 2 * L_,
                                                        attn + 2 * SLOT);
    finalize_all_k<<<dim3(64, 64, 1), 256, 0, stream>>>(tb3, rowsum + 3 * L_,
                                                        attn + 3 * SLOT);
  }
}

// Round 3
// 662.657 us; speedup vs baseline: 1.2268x; 1.0091x over previous
//
#include <hip/hip_runtime.h>

#define B_ 4
#define C_ 512
#define L_ 4096

typedef __attribute__((ext_vector_type(8))) short bf16x8;
typedef __attribute__((ext_vector_type(4))) float f32x4;

#define MFMA16(a, b, c) __builtin_amdgcn_mfma_f32_16x16x32_bf16(a, b, c, 0, 0, 0)

static __device__ __forceinline__ unsigned short f2bf_rne(float f) {
  unsigned u = __float_as_uint(f);
  u += 0x7FFFu + ((u >> 16) & 1u);  // round-to-nearest-even
  return (unsigned short)(u >> 16);
}
static __device__ __forceinline__ unsigned pack_rne(float a, float b) {
  return (unsigned)f2bf_rne(a) | ((unsigned)f2bf_rne(b) << 16);
}
static __device__ __forceinline__ float bflo2f(unsigned w) {
  return __uint_as_float(w << 16);
}
static __device__ __forceinline__ float bfhi2f(unsigned w) {
  return __uint_as_float(w & 0xFFFF0000u);
}

// async global -> LDS, 16 B/lane; LDS dest = wave-uniform base + lane*16.
static __device__ __forceinline__ void g2lds16(const unsigned short* g,
                                               unsigned short* l) {
  __builtin_amdgcn_global_load_lds(
      (const __attribute__((address_space(1))) unsigned int*)g,
      (__attribute__((address_space(3))) unsigned int*)l, 16, 0, 0);
}

// ---------------------------------------------------------------------------
// K0: Q,K fp32 (C,L) -> Qt,Kt bf16 (L,C).  grid (L/64, C/64, B*2), block 256
// ---------------------------------------------------------------------------
__global__ __launch_bounds__(256) void transpose_cast_k(
    const float* __restrict__ Q, const float* __restrict__ K,
    unsigned short* __restrict__ Qt, unsigned short* __restrict__ Kt) {
  int zb = blockIdx.z;
  int b = zb >> 1;
  const float* src = ((zb & 1) ? K : Q) + (size_t)b * C_ * L_;
  unsigned short* dst = ((zb & 1) ? Kt : Qt) + (size_t)b * L_ * C_;
  int i0 = blockIdx.x * 64, c0 = blockIdx.y * 64;
  __shared__ float tile[64][65];
  int t = threadIdx.x;
  int cr = t >> 2, ig = (t & 3) * 16;
  const float* s = src + (size_t)(c0 + cr) * L_ + i0 + ig;
#pragma unroll
  for (int q = 0; q < 4; ++q) {
    float4 v = *(const float4*)(s + 4 * q);
    tile[cr][ig + 4 * q + 0] = v.x;
    tile[cr][ig + 4 * q + 1] = v.y;
    tile[cr][ig + 4 * q + 2] = v.z;
    tile[cr][ig + 4 * q + 3] = v.w;
  }
  __syncthreads();
  int ir = t >> 2, cg = (t & 3) * 16;
  unsigned wds[8];
#pragma unroll
  for (int k = 0; k < 8; ++k)
    wds[k] = pack_rne(tile[cg + 2 * k][ir], tile[cg + 2 * k + 1][ir]);
  unsigned short* d = dst + (size_t)(i0 + ir) * C_ + c0 + cg;
  uint4 o0, o1;
  o0.x = wds[0]; o0.y = wds[1]; o0.z = wds[2]; o0.w = wds[3];
  o1.x = wds[4]; o1.y = wds[5]; o1.z = wds[6]; o1.w = wds[7];
  *(uint4*)d = o0;
  *(uint4*)(d + 8) = o1;
}

// ---------------------------------------------------------------------------
// K0b: Vb[b,c,j] = bf16(V[b,c,j] * mask[b,j])
// ---------------------------------------------------------------------------
__global__ __launch_bounds__(256) void cast_v_k(
    const float* __restrict__ V, const float* __restrict__ mask,
    unsigned short* __restrict__ Vb) {
  size_t idx = ((size_t)blockIdx.x * 256 + threadIdx.x) * 8;
  int b = (int)(idx >> 21);  // C*L = 2^21
  int j = (int)(idx & (L_ - 1));
  float4 v0 = *(const float4*)(V + idx);
  float4 v1 = *(const float4*)(V + idx + 4);
  const float* m = mask + (size_t)b * L_ + j;
  float4 m0 = *(const float4*)m;
  float4 m1 = *(const float4*)(m + 4);
  uint4 o;
  o.x = pack_rne(v0.x * m0.x, v0.y * m0.y);
  o.y = pack_rne(v0.z * m0.z, v0.w * m0.w);
  o.z = pack_rne(v1.x * m1.x, v1.y * m1.y);
  o.w = pack_rne(v1.z * m1.z, v1.w * m1.w);
  *(uint4*)(Vb + idx) = o;
}

// ===========================================================================
// 256x256 8-phase NT GEMM mainloop (T1..T5).  BK=64, 8 waves (2Mx4N),
// LDS per operand: [2 dbuf][2 kc][256 rows][32 k] bf16 = 64 KB (128 KB total).
// st_16x32 swizzle: elem index e ^= ((e>>8)&1)<<4, applied to BOTH the
// global_load_lds source (pre-swizzle) and the ds_read address.
// Counted vmcnt(6) at phases 4/8 only; raw s_barriers; setprio around MFMA.
// Half-stream order per tile: B.h0, B.h1, A.h0, A.h1 (2 loads each).
// Staging schedule (iteration computes tiles X, X+1):
//  p1:(X+1,A1) p2:(X+2,B0) p3:(X+2,B1) p4:(X+2,A0)+VM6
//  p5:(X+2,A1) p6:(X+3,B0) p7:(X+3,B1) p8:(X+3,A0)+VM6
// Region safety: all B reads of a tile happen in its first phase, A reads by
// its third phase -> every stage lands strictly after the region's last read.
// ===========================================================================
__device__ __forceinline__ void gemm_8phase(
    const unsigned short* __restrict__ Ab,
    const unsigned short* __restrict__ Bb, int lda, int ldb, int Kdim,
    unsigned short* sA, unsigned short* sB, f32x4 (&acc)[8][4]) {
  const int t = threadIdx.x;
  const int lane = t & 63;
  const int quad = lane >> 4;
  const int l15 = lane & 15;
  const int w = t >> 6;
  const int wm = (w & 1) * 128;
  const int wn = (w >> 1) * 64;
  // pre-swizzled staging source coords (inverse of the ds_read swizzle)
  const int et = (t * 8) ^ (((t >> 5) & 1) << 4);
  const int srw = et >> 5;  // row within 128-row half
  const int scl = et & 31;  // k within 32-wide kc chunk
  const int nt = Kdim >> 6;

  auto stage = [&](int nom, int hh) {
    int st = nom < nt ? nom : nt - 1;  // clamp keeps addresses valid & vmcnt uniform
    int db = nom & 1;
    int h = hh & 1;
    const unsigned short* g;
    unsigned short* l;
    if (hh < 2) {
      g = Bb + (size_t)(h * 128 + srw) * ldb + st * 64 + scl;
      l = sB + db * 16384 + h * 4096 + t * 8;
    } else {
      g = Ab + (size_t)(h * 128 + srw) * lda + st * 64 + scl;
      l = sA + db * 16384 + h * 4096 + t * 8;
    }
    g2lds16(g, l);            // kc = 0
    g2lds16(g + 32, l + 8192);  // kc = 1
  };
  auto rd = [&](const unsigned short* s, int db, int kc, int row) -> bf16x8 {
    int e = db * 16384 + kc * 8192 + row * 32 + quad * 8;
    e ^= ((e >> 8) & 1) << 4;  // st_16x32 swizzle
    return *(const bf16x8*)(s + e);
  };

  bf16x8 aF[4][2], b0[2][2], b1[2][2];
  auto rdA4 = [&](int db, int mbase) {
#pragma unroll
    for (int m = 0; m < 4; ++m)
#pragma unroll
      for (int kc = 0; kc < 2; ++kc)
        aF[m][kc] = rd(sA, db, kc, wm + (mbase + m) * 16 + l15);
  };
  auto rdB2 = [&](bf16x8 (&bf)[2][2], int db, int nbase) {
#pragma unroll
    for (int n = 0; n < 2; ++n)
#pragma unroll
      for (int kc = 0; kc < 2; ++kc)
        bf[n][kc] = rd(sB, db, kc, wn + (nbase + n) * 16 + l15);
  };
  auto mfma8 = [&](bf16x8 (&bf)[2][2], int mo, int no) {
    __builtin_amdgcn_s_setprio(1);
#pragma unroll
    for (int m = 0; m < 4; ++m)
#pragma unroll
      for (int n = 0; n < 2; ++n) {
        acc[mo + m][no + n] = MFMA16(aF[m][0], bf[n][0], acc[mo + m][no + n]);
        acc[mo + m][no + n] = MFMA16(aF[m][1], bf[n][1], acc[mo + m][no + n]);
      }
    __builtin_amdgcn_s_setprio(0);
  };

#define BAR_() __builtin_amdgcn_s_barrier()
#define LGKM0_() asm volatile("s_waitcnt lgkmcnt(0)" ::: "memory")
#define VM6_() asm volatile("s_waitcnt vmcnt(6)" ::: "memory")
#define SCHED0_() __builtin_amdgcn_sched_barrier(0)

  // prologue: tile0 fully + 3 halves of tile1 in flight
  stage(0, 0); stage(0, 1); stage(0, 2); stage(0, 3);
  asm volatile("s_waitcnt vmcnt(4)" ::: "memory");
  stage(1, 0); stage(1, 1); stage(1, 2);
  asm volatile("s_waitcnt vmcnt(6)" ::: "memory");
  BAR_();

  const int ni = nt >> 1;
  for (int i = 0; i < ni; ++i) {
    const int X = 2 * i;
    // p1: tile X (db0) — read A-half(own,m0-3) + ALL B frags
    rdA4(0, 0); rdB2(b0, 0, 0); rdB2(b1, 0, 2);
    stage(X + 1, 3);
    BAR_(); LGKM0_();
    mfma8(b0, 0, 0);
    BAR_();
    // p2
    stage(X + 2, 0);
    BAR_();
    mfma8(b1, 0, 2);
    BAR_();
    // p3
    rdA4(0, 4);
    stage(X + 2, 1);
    BAR_(); LGKM0_();
    mfma8(b0, 4, 0);
    BAR_();
    // p4
    stage(X + 2, 2);
    VM6_(); BAR_();
    mfma8(b1, 4, 2);
    BAR_(); SCHED0_();
    // p5: tile X+1 (db1)
    rdA4(1, 0); rdB2(b0, 1, 0); rdB2(b1, 1, 2);
    stage(X + 2, 3);
    BAR_(); LGKM0_();
    mfma8(b0, 0, 0);
    BAR_();
    // p6
    stage(X + 3, 0);
    BAR_();
    mfma8(b1, 0, 2);
    BAR_();
    // p7
    rdA4(1, 4);
    stage(X + 3, 1);
    BAR_(); LGKM0_();
    mfma8(b0, 4, 0);
    BAR_();
    // p8
    stage(X + 3, 2);
    VM6_(); BAR_();
    mfma8(b1, 4, 2);
    BAR_(); SCHED0_();
  }
  asm volatile("s_waitcnt vmcnt(0)" ::: "memory");  // drain DMA before exit
}

// ---------------------------------------------------------------------------
// K1 (8-phase): E = Qt*Kt^T; tv = exp(E*scale + log(mask+1e-6));
// tb = bf16(tv*mask); fp32 rowsum atomics.  grid (16,16,4), block 512
// ---------------------------------------------------------------------------
__global__ __launch_bounds__(512, 2) void gemm1_8p_k(
    const unsigned short* __restrict__ Qt, const unsigned short* __restrict__ Kt,
    const float* __restrict__ mask, unsigned short* __restrict__ t0,
    unsigned short* __restrict__ t1, unsigned short* __restrict__ t2,
    unsigned short* __restrict__ t3, float* __restrict__ rowsum) {
  __shared__ unsigned short sA[32768];
  __shared__ unsigned short sB[32768];
  // bijective XCD swizzle (nwg=1024, 8 XCDs)
  int flat = blockIdx.x + (blockIdx.y << 4) + (blockIdx.z << 8);
  int swz = (flat & 7) * 128 + (flat >> 3);
  int bx = swz & 15, by = (swz >> 4) & 15, b = swz >> 8;
  unsigned short* tbb = (b == 0) ? t0 : (b == 1) ? t1 : (b == 2) ? t2 : t3;
  int i0 = by * 256, j0 = bx * 256;
  f32x4 acc[8][4] = {};
  gemm_8phase(Qt + (size_t)b * L_ * C_ + (size_t)i0 * C_,
              Kt + (size_t)b * L_ * C_ + (size_t)j0 * C_, C_, C_, C_, sA, sB,
              acc);
  int t = threadIdx.x;
  int lane = t & 63;
  int quad = lane >> 4;
  int l15 = lane & 15;
  int w = t >> 6;
  int wm = (w & 1) * 128;
  int wn = (w >> 1) * 64;
  const float scale = 0.04419417382415922f;  // 1/sqrt(512)
  float lm[4], mv[4];
#pragma unroll
  for (int n = 0; n < 4; ++n) {
    int j = j0 + wn + n * 16 + l15;
    float m = mask[(size_t)b * L_ + j];
    mv[n] = m;
    lm[n] = __logf(m + 1e-6f);
  }
  float rs[8][4];
#pragma unroll
  for (int m = 0; m < 8; ++m)
#pragma unroll
    for (int r = 0; r < 4; ++r) rs[m][r] = 0.f;
#pragma unroll
  for (int m = 0; m < 8; ++m) {
    int irow = i0 + wm + m * 16 + quad * 4;  // C/D: row = quad*4 + reg
#pragma unroll
    for (int r = 0; r < 4; ++r) {
      size_t ro = (size_t)(irow + r) * L_;
#pragma unroll
      for (int n = 0; n < 4; ++n) {
        float x = fminf(acc[m][n][r] * scale + lm[n], 60.f);
        float tv = __expf(x);  // |logit| small: max-free softmax is safe
        rs[m][r] += tv;
        tbb[ro + j0 + wn + n * 16 + l15] = f2bf_rne(tv * mv[n]);
      }
    }
  }
#pragma unroll
  for (int mm = 1; mm < 16; mm <<= 1)
#pragma unroll
    for (int m = 0; m < 8; ++m)
#pragma unroll
      for (int r = 0; r < 4; ++r) rs[m][r] += __shfl_xor(rs[m][r], mm, 64);
  if (l15 == 0) {
    float* rb = rowsum + (size_t)b * L_ + i0 + wm;
#pragma unroll
    for (int m = 0; m < 8; ++m)
#pragma unroll
      for (int r = 0; r < 4; ++r)
        atomicAdd(&rb[m * 16 + quad * 4 + r], rs[m][r]);
  }
}

// ---------------------------------------------------------------------------
// K2 (8-phase): out[c,i] = inv[i]*sum_j Vb[c,j]*tb[i,j].  split-K=2 over j;
// ks=0 -> out, ks=1 -> out2 (combined later).  grid (16,2,8), block 512
// ---------------------------------------------------------------------------
__global__ __launch_bounds__(512, 2) void gemm2_8p_k(
    const unsigned short* __restrict__ Vb, const unsigned short* __restrict__ t0,
    const unsigned short* __restrict__ t1, const unsigned short* __restrict__ t2,
    const unsigned short* __restrict__ t3, const float* __restrict__ rowsum,
    float* __restrict__ out, float* __restrict__ out2) {
  __shared__ unsigned short sA[32768];
  __shared__ unsigned short sB[32768];
  // bijective XCD swizzle (nwg=256)
  int flat = blockIdx.x + (blockIdx.y << 4) + (blockIdx.z << 5);
  int swz = (flat & 7) * 32 + (flat >> 3);
  int ix = swz & 15, cy = (swz >> 4) & 1, z = swz >> 5;
  int b = z & 3, ks = z >> 2;
  const unsigned short* tbb =
      (b == 0) ? t0 : (b == 1) ? t1 : (b == 2) ? t2 : t3;
  int i0 = ix * 256, c0 = cy * 256;
  f32x4 acc[8][4] = {};
  gemm_8phase(Vb + (size_t)b * C_ * L_ + (size_t)c0 * L_ + ks * (L_ / 2),
              tbb + (size_t)i0 * L_ + ks * (L_ / 2), L_, L_, L_ / 2, sA, sB,
              acc);
  int t = threadIdx.x;
  int lane = t & 63;
  int quad = lane >> 4;
  int l15 = lane & 15;
  int w = t >> 6;
  int wm = (w & 1) * 128;
  int wn = (w >> 1) * 64;
  float invv[4];
#pragma unroll
  for (int n = 0; n < 4; ++n)
    invv[n] = 1.0f / rowsum[(size_t)b * L_ + i0 + wn + n * 16 + l15];
  float* ob = (ks ? out2 : out) + (size_t)b * C_ * L_;
#pragma unroll
  for (int m = 0; m < 8; ++m) {
    int crow = c0 + wm + m * 16 + quad * 4;
#pragma unroll
    for (int r = 0; r < 4; ++r) {
      size_t ro = (size_t)(crow + r) * L_;
#pragma unroll
      for (int n = 0; n < 4; ++n)
        ob[ro + i0 + wn + n * 16 + l15] = acc[m][n][r] * invv[n];
    }
  }
}

// ---------------------------------------------------------------------------
// K2b: out += out2  (split-K combine).  grid (B*C*L)/2048, block 256.
// ---------------------------------------------------------------------------
__global__ __launch_bounds__(256) void combine_out_k(
    float* __restrict__ out, const float* __restrict__ out2) {
  size_t idx = ((size_t)blockIdx.x * 256 + threadIdx.x) * 8;
  float4 a0 = *(const float4*)(out + idx);
  float4 a1 = *(const float4*)(out + idx + 4);
  float4 b0 = *(const float4*)(out2 + idx);
  float4 b1 = *(const float4*)(out2 + idx + 4);
  a0.x += b0.x; a0.y += b0.y; a0.z += b0.z; a0.w += b0.w;
  a1.x += b1.x; a1.y += b1.y; a1.z += b1.z; a1.w += b1.w;
  *(float4*)(out + idx) = a0;
  *(float4*)(out + idx + 4) = a1;
}

// ---------------------------------------------------------------------------
// K3: attn[b][j,i] = bf2f(tb[b][i,j]) / rowsum[b][i]   (out-of-place).
// grid (64, 64, nb), block 256.  For nb>1, tb/attn must not alias.
// ---------------------------------------------------------------------------
__global__ __launch_bounds__(256) void finalize_all_k(
    const unsigned short* __restrict__ tb, const float* __restrict__ rowsum,
    float* __restrict__ attn) {
  int b = blockIdx.z;
  const unsigned short* src = tb + (size_t)b * L_ * L_;
  const float* rs = rowsum + (size_t)b * L_;
  float* dst = attn + (size_t)b * L_ * L_;
  int jt = blockIdx.x, it = blockIdx.y;
  __shared__ float tileT[64][65];
  int t = threadIdx.x;
  int r = t >> 2, cg = (t & 3) * 16;
  int i = it * 64 + r;
  float inv = 1.0f / rs[i];
  const unsigned short* sp = src + (size_t)i * L_ + jt * 64 + cg;
  uint4 u0 = *(const uint4*)sp;
  uint4 u1 = *(const uint4*)(sp + 8);
  const unsigned* w0 = (const unsigned*)&u0;
  const unsigned* w1 = (const unsigned*)&u1;
#pragma unroll
  for (int k = 0; k < 4; ++k) {
    tileT[cg + 2 * k + 0][r] = bflo2f(w0[k]) * inv;
    tileT[cg + 2 * k + 1][r] = bfhi2f(w0[k]) * inv;
    tileT[cg + 8 + 2 * k + 0][r] = bflo2f(w1[k]) * inv;
    tileT[cg + 8 + 2 * k + 1][r] = bfhi2f(w1[k]) * inv;
  }
  __syncthreads();
  float* dp = dst + (size_t)(jt * 64 + r) * L_ + it * 64 + cg;
#pragma unroll
  for (int q = 0; q < 4; ++q) {
    float4 o;
    o.x = tileT[r][cg + 4 * q + 0];
    o.y = tileT[r][cg + 4 * q + 1];
    o.z = tileT[r][cg + 4 * q + 2];
    o.w = tileT[r][cg + 4 * q + 3];
    *(float4*)(dp + 4 * q) = o;
  }
}

// ===========================================================================
// FALLBACK tier (small ws): round-2 proven 128x128 2-phase pipeline.
// ===========================================================================
__device__ __forceinline__ void gemm_mainloop64(
    const unsigned short* Ab, const unsigned short* Bb, int lda, int ldb,
    int Kdim, unsigned short* sA, unsigned short* sB, f32x4 acc[4][4]) {
  int t = threadIdx.x;
  const unsigned short* pA[4];
  const unsigned short* pB[4];
#pragma unroll
  for (int c = 0; c < 4; ++c) {
    int e = t * 8 + c * 2048;
    int kc = e >> 12;
    int rem = e & 4095;
    int row = rem >> 5;
    int col = rem & 31;
    int off = kc * 32 + col;
    pA[c] = Ab + (size_t)row * lda + off;
    pB[c] = Bb + (size_t)row * ldb + off;
  }
  int lane = t & 63;
  int quad = lane >> 4;
  int l15 = lane & 15;
  int w = t >> 6;
  int wm = (w & 1) * 64;
  int wn = (w >> 1) * 64;
  for (int kk = 0; kk < Kdim; kk += 64) {
    __syncthreads();
#pragma unroll
    for (int c = 0; c < 4; ++c) g2lds16(pA[c] + kk, sA + t * 8 + c * 2048);
#pragma unroll
    for (int c = 0; c < 4; ++c) g2lds16(pB[c] + kk, sB + t * 8 + c * 2048);
    __syncthreads();
#pragma unroll
    for (int kc = 0; kc < 2; ++kc) {
      bf16x8 aF[4], bF[4];
#pragma unroll
      for (int ti = 0; ti < 4; ++ti)
        aF[ti] = *(const bf16x8*)(sA + kc * 4096 +
                                  (wm + ti * 16 + l15) * 32 + quad * 8);
#pragma unroll
      for (int tj = 0; tj < 4; ++tj)
        bF[tj] = *(const bf16x8*)(sB + kc * 4096 +
                                  (wn + tj * 16 + l15) * 32 + quad * 8);
#pragma unroll
      for (int ti = 0; ti < 4; ++ti)
#pragma unroll
        for (int tj = 0; tj < 4; ++tj)
          acc[ti][tj] = MFMA16(aF[ti], bF[tj], acc[ti][tj]);
    }
  }
}

__global__ __launch_bounds__(256) void gemm1_bf_k(
    const unsigned short* __restrict__ Qt, const unsigned short* __restrict__ Kt,
    const float* __restrict__ mask, unsigned short* __restrict__ t0,
    unsigned short* __restrict__ t1, unsigned short* __restrict__ t2,
    unsigned short* __restrict__ t3, float* __restrict__ rowsum) {
  int b = blockIdx.z;
  unsigned short* tbb = (b == 0) ? t0 : (b == 1) ? t1 : (b == 2) ? t2 : t3;
  int i0 = blockIdx.y * 128;
  int j0 = blockIdx.x * 128;
  __shared__ unsigned short sA[8192];
  __shared__ unsigned short sB[8192];
  f32x4 acc[4][4] = {};
  gemm_mainloop64(Qt + (size_t)b * L_ * C_ + (size_t)i0 * C_,
                  Kt + (size_t)b * L_ * C_ + (size_t)j0 * C_, C_, C_, C_, sA,
                  sB, acc);
  int t = threadIdx.x;
  int lane = t & 63;
  int quad = lane >> 4;
  int l15 = lane & 15;
  int w = t >> 6;
  int wm = (w & 1) * 64;
  int wn = (w >> 1) * 64;
  const float scale = 0.04419417382415922f;
  float lm[4], mv[4];
#pragma unroll
  for (int tj = 0; tj < 4; ++tj) {
    int j = j0 + wn + tj * 16 + l15;
    float m = mask[(size_t)b * L_ + j];
    mv[tj] = m;
    lm[tj] = __logf(m + 1e-6f);
  }
  float rs[16];
#pragma unroll
  for (int q = 0; q < 16; ++q) rs[q] = 0.f;
#pragma unroll
  for (int ti = 0; ti < 4; ++ti) {
    int irow = i0 + wm + ti * 16 + quad * 4;
#pragma unroll
    for (int r = 0; r < 4; ++r) {
      size_t ro = (size_t)(irow + r) * L_;
#pragma unroll
      for (int tj = 0; tj < 4; ++tj) {
        float x = fminf(acc[ti][tj][r] * scale + lm[tj], 60.f);
        float tv = __expf(x);
        rs[ti * 4 + r] += tv;
        tbb[ro + j0 + wn + tj * 16 + l15] = f2bf_rne(tv * mv[tj]);
      }
    }
  }
#pragma unroll
  for (int m = 1; m < 16; m <<= 1)
#pragma unroll
    for (int q = 0; q < 16; ++q) rs[q] += __shfl_xor(rs[q], m, 64);
  if (l15 == 0) {
    float* rb = rowsum + (size_t)b * L_ + i0 + wm;
#pragma unroll
    for (int ti = 0; ti < 4; ++ti)
#pragma unroll
      for (int r = 0; r < 4; ++r)
        atomicAdd(&rb[ti * 16 + quad * 4 + r], rs[ti * 4 + r]);
  }
}

__global__ __launch_bounds__(256) void gemm2_bf_k(
    const unsigned short* __restrict__ Vb, const unsigned short* __restrict__ t0,
    const unsigned short* __restrict__ t1, const unsigned short* __restrict__ t2,
    const unsigned short* __restrict__ t3, const float* __restrict__ rowsum,
    float* __restrict__ out) {
  int z = blockIdx.z;
  int b = z & 3;
  int ks = z >> 2;
  const unsigned short* tbb =
      (b == 0) ? t0 : (b == 1) ? t1 : (b == 2) ? t2 : t3;
  int c0 = blockIdx.y * 128;
  int i0 = blockIdx.x * 128;
  __shared__ unsigned short sA[8192];
  __shared__ unsigned short sB[8192];
  f32x4 acc[4][4] = {};
  gemm_mainloop64(Vb + (size_t)b * C_ * L_ + (size_t)c0 * L_ + ks * (L_ / 2),
                  tbb + (size_t)i0 * L_ + ks * (L_ / 2), L_, L_, L_ / 2, sA, sB,
                  acc);
  int t = threadIdx.x;
  int lane = t & 63;
  int quad = lane >> 4;
  int l15 = lane & 15;
  int w = t >> 6;
  int wm = (w & 1) * 64;
  int wn = (w >> 1) * 64;
  float invv[4];
#pragma unroll
  for (int tj = 0; tj < 4; ++tj)
    invv[tj] = 1.0f / rowsum[(size_t)b * L_ + i0 + wn + tj * 16 + l15];
  float* ob = out + (size_t)b * C_ * L_;
#pragma unroll
  for (int ti = 0; ti < 4; ++ti) {
    int crow = c0 + wm + ti * 16 + quad * 4;
#pragma unroll
    for (int r = 0; r < 4; ++r) {
      size_t ro = (size_t)(crow + r) * L_;
#pragma unroll
      for (int tj = 0; tj < 4; ++tj)
        atomicAdd(&ob[ro + i0 + wn + tj * 16 + l15],
                  acc[ti][tj][r] * invv[tj]);
    }
  }
}

extern "C" void kernel_launch(void* const* d_in, const int* in_sizes, int n_in,
                              void* d_out, int out_size, void* d_ws,
                              size_t ws_size, hipStream_t stream) {
  const float* Q = (const float*)d_in[0];
  const float* K = (const float*)d_in[1];
  const float* V = (const float*)d_in[2];
  const float* mask = (const float*)d_in[3];

  float* out = (float*)d_out;                // (B,C,L) fp32
  float* attn = out + (size_t)B_ * C_ * L_;  // (B,L,L) fp32

  const size_t NQ = (size_t)B_ * L_ * C_;    // elems per bf16 operand tensor
  const size_t SLOT = (size_t)L_ * L_;       // elems per (L,L) matrix
  unsigned short* Qt = (unsigned short*)d_ws;
  unsigned short* Kt = Qt + NQ;
  unsigned short* Vb = Kt + NQ;
  float* rowsum = (float*)(Vb + NQ);
  unsigned short* wtail = (unsigned short*)(rowsum + (size_t)B_ * L_);

  // tier-1: tb (B,L,L) bf16 + out2 (B,C,L) fp32 all in dedicated workspace
  const size_t need1 =
      NQ * 2 * 3 + (size_t)B_ * L_ * 4 + (size_t)B_ * SLOT * 2 + NQ * 4;

  hipMemsetAsync(rowsum, 0, (size_t)B_ * L_ * sizeof(float), stream);
  transpose_cast_k<<<dim3(L_ / 64, C_ / 64, B_ * 2), 256, 0, stream>>>(Q, K, Qt,
                                                                       Kt);
  cast_v_k<<<dim3((B_ * C_ * L_) / 2048), 256, 0, stream>>>(V, mask, Vb);

  if (ws_size >= need1) {
    unsigned short* tb = wtail;                      // (B,L,L) bf16
    float* out2 = (float*)(tb + (size_t)B_ * SLOT);  // (B,C,L) fp32
    gemm1_8p_k<<<dim3(16, 16, B_), 512, 0, stream>>>(
        Qt, Kt, mask, tb, tb + SLOT, tb + 2 * SLOT, tb + 3 * SLOT, rowsum);
    gemm2_8p_k<<<dim3(16, 2, B_ * 2), 512, 0, stream>>>(
        Vb, tb, tb + SLOT, tb + 2 * SLOT, tb + 3 * SLOT, rowsum, out, out2);
    combine_out_k<<<dim3((B_ * C_ * L_) / 2048), 256, 0, stream>>>(out, out2);
    finalize_all_k<<<dim3(64, 64, B_), 256, 0, stream>>>(tb, rowsum, attn);
  } else {
    // fallback tier: tb parked in not-yet-final attn slots (round-1 layout).
    unsigned short* tb0 = (unsigned short*)(attn + 2 * SLOT);
    unsigned short* tb1 = (unsigned short*)(attn + 3 * SLOT);
    unsigned short* tb2 = (unsigned short*)(attn + 3 * SLOT + SLOT / 2);
    unsigned short* tb3 = wtail;
    hipMemsetAsync(out, 0, (size_t)B_ * C_ * L_ * sizeof(float), stream);
    gemm1_bf_k<<<dim3(L_ / 128, L_ / 128, B_), 256, 0, stream>>>(
        Qt, Kt, mask, tb0, tb1, tb2, tb3, rowsum);
    gemm2_bf_k<<<dim3(L_ / 128, C_ / 128, B_ * 2), 256, 0, stream>>>(
        Vb, tb0, tb1, tb2, tb3, rowsum, out);
    finalize_all_k<<<dim3(64, 64, 1), 256, 0, stream>>>(tb0, rowsum, attn);
    finalize_all_k<<<dim3(64, 64, 1), 256, 0, stream>>>(tb1, rowsum + L_,
                                                        attn + SLOT);
    finalize_all_k<<<dim3(64, 64, 1), 256, 0, stream>>>(tb2, rowsum + 2 * L_,
                                                        attn + 2 * SLOT);
    finalize_all_k<<<dim3(64, 64, 1), 256, 0, stream>>>(tb3, rowsum + 3 * L_,
                                                        attn + 3 * SLOT);
  }
}